// Round 5
// baseline (443.632 us; speedup 1.0000x reference)
//
#include <hip/hip_runtime.h>

#define B_ 8
#define T_ 4096
#define C_ 128
#define HS_ 64

typedef _Float16 f16;
typedef _Float16 f16x8 __attribute__((ext_vector_type(8)));
typedef _Float16 f16x4 __attribute__((ext_vector_type(4)));
typedef float f32x4 __attribute__((ext_vector_type(4)));

#define MFMA32(a, b, c) __builtin_amdgcn_mfma_f32_16x16x32_f16(a, b, c, 0, 0, 0)
#define MFMA16(a, b, c) __builtin_amdgcn_mfma_f32_16x16x16f16(a, b, c, 0, 0, 0)

// ---------------------------------------------------------------------------
// Prep: WT[j][c] f16, j in [0,192): 0-63 Wq (scaled by 1/sqrt(C)), 64-127 Wk,
// 128-191 Wv.  WT row-major [192][128].
// ---------------------------------------------------------------------------
__global__ void k_wprep(const float* __restrict__ Wq, const float* __restrict__ Wk,
                        const float* __restrict__ Wv, f16* __restrict__ WT) {
    int idx = blockIdx.x * 256 + threadIdx.x;
    if (idx >= 192 * C_) return;
    int j = idx >> 7, c = idx & 127;
    const float* W = (j < 64) ? Wq : (j < 128 ? Wk : Wv);
    float v = W[c * HS_ + (j & 63)];
    if (j < 64) v *= 0.08838834764831845f;     // 1/sqrt(128), folded into q
    WT[idx] = (f16)v;
}

// ---------------------------------------------------------------------------
// QKV projection + RoPE.  OUT^T = WT · x^T via 16x16x32 MFMA.
// ---------------------------------------------------------------------------
__global__ __launch_bounds__(256) void k_qkv(const float* __restrict__ x,
        const f16* __restrict__ WT, const float* __restrict__ fcos,
        const float* __restrict__ fsin, f16* __restrict__ Q,
        f16* __restrict__ K, f16* __restrict__ VT) {
    const int b = blockIdx.y;
    const int w = threadIdx.x >> 6, lane = threadIdx.x & 63;
    const int col = lane & 15, g = lane >> 4;
    const int t = blockIdx.x * 64 + w * 16 + col;

    f16x8 bx[4];
    const float* xrow = x + ((size_t)(b * T_ + t)) * C_;
#pragma unroll
    for (int cc = 0; cc < 4; ++cc) {
        float4 x0 = *(const float4*)(xrow + cc * 32 + g * 8);
        float4 x1 = *(const float4*)(xrow + cc * 32 + g * 8 + 4);
        f16x8 v;
        v[0] = (f16)x0.x; v[1] = (f16)x0.y; v[2] = (f16)x0.z; v[3] = (f16)x0.w;
        v[4] = (f16)x1.x; v[5] = (f16)x1.y; v[6] = (f16)x1.z; v[7] = (f16)x1.w;
        bx[cc] = v;
    }

#pragma unroll
    for (int jt = 0; jt < 12; ++jt) {
        f32x4 acc = {0.f, 0.f, 0.f, 0.f};
#pragma unroll
        for (int cc = 0; cc < 4; ++cc) {
            f16x8 aw = *(const f16x8*)(WT + (size_t)(jt * 16 + col) * C_ + cc * 32 + g * 8);
            acc = MFMA32(aw, bx[cc], acc);
        }
        if (jt < 8) {
            const int hbase = (jt & 3) * 16 + g * 4;   // even head-dim base
            const int i0 = hbase >> 1;
            float c0 = fcos[t * 32 + i0],     s0 = fsin[t * 32 + i0];
            float c1 = fcos[t * 32 + i0 + 1], s1 = fsin[t * 32 + i0 + 1];
            float o0 = acc[0] * c0 - acc[1] * s0;
            float o1 = acc[0] * s0 + acc[1] * c0;
            float o2 = acc[2] * c1 - acc[3] * s1;
            float o3 = acc[2] * s1 + acc[3] * c1;
            f16x4 st; st[0] = (f16)o0; st[1] = (f16)o1; st[2] = (f16)o2; st[3] = (f16)o3;
            f16* dst = (jt < 4 ? Q : K);
            *(f16x4*)(dst + ((size_t)(b * T_ + t)) * HS_ + hbase) = st;
        } else {
            const int dbase = (jt - 8) * 16 + g * 4;
#pragma unroll
            for (int r = 0; r < 4; ++r)
                VT[((size_t)(b * HS_ + dbase + r)) * T_ + t] = (f16)acc[r];
        }
    }
}

// ---------------------------------------------------------------------------
// Flash attention, KVBLK=64, register double-buffered prefetch.
// Wave = 16 q rows. S^T = K·Q^T (16x16x32, 4 subtiles); softmax over 16
// in-lane regs + shfl 16/32; P^T feeds 16x16x16 PV (O^T = V^T·P^T).
// No LDS, no barriers. Output f32.
// ---------------------------------------------------------------------------
struct Tile {
    f16x8 k[8];     // 4 subtiles x (2 x f16x8)
    int4  mk[4];    // padding mask, 4 ints per subtile (this lane's g*4 slice)
    f16x4 v[16];    // [sub][mt]: VT[d=col+16*mt][kv0+sub*16+g*4 ..+3]
};

__device__ __forceinline__ void load_tile(Tile& t_, int it, const f16* __restrict__ kb,
        const int* __restrict__ mrow, const f16* __restrict__ vb, int col, int g) {
    const int kv0 = it * 64;
#pragma unroll
    for (int sub = 0; sub < 4; ++sub) {
        const f16* krow = kb + (size_t)(kv0 + sub * 16 + col) * HS_;
        t_.k[sub * 2]     = *(const f16x8*)(krow + g * 8);
        t_.k[sub * 2 + 1] = *(const f16x8*)(krow + 32 + g * 8);
        t_.mk[sub] = *(const int4*)(mrow + kv0 + sub * 16 + g * 4);
#pragma unroll
        for (int mt = 0; mt < 4; ++mt)
            t_.v[sub * 4 + mt] = *(const f16x4*)(vb + (size_t)(col + 16 * mt) * T_ + kv0 + sub * 16 + g * 4);
    }
}

__device__ __forceinline__ void compute_tile(const Tile& t_, int it, bool last,
        f16x8 bq0, f16x8 bq1, int qc, int g,
        float& m, float& lsum, f32x4& o0, f32x4& o1, f32x4& o2, f32x4& o3) {
    float sv[16];
#pragma unroll
    for (int sub = 0; sub < 4; ++sub) {
        f32x4 s = {0.f, 0.f, 0.f, 0.f};
        s = MFMA32(t_.k[sub * 2], bq0, s);
        s = MFMA32(t_.k[sub * 2 + 1], bq1, s);
        const int4 mk = t_.mk[sub];
        const int kbase = it * 64 + sub * 16 + g * 4;
        bool c0 = mk.x != 0, c1 = mk.y != 0, c2 = mk.z != 0, c3 = mk.w != 0;
        if (last) {
            c0 = c0 && (kbase + 0 <= qc); c1 = c1 && (kbase + 1 <= qc);
            c2 = c2 && (kbase + 2 <= qc); c3 = c3 && (kbase + 3 <= qc);
        }
        sv[sub * 4 + 0] = c0 ? s.x : -1e30f;
        sv[sub * 4 + 1] = c1 ? s.y : -1e30f;
        sv[sub * 4 + 2] = c2 ? s.z : -1e30f;
        sv[sub * 4 + 3] = c3 ? s.w : -1e30f;
    }
    // max over 16 in-lane + cross-g
    float t0 = fmaxf(fmaxf(sv[0], sv[1]),   fmaxf(sv[2], sv[3]));
    float t1 = fmaxf(fmaxf(sv[4], sv[5]),   fmaxf(sv[6], sv[7]));
    float t2 = fmaxf(fmaxf(sv[8], sv[9]),   fmaxf(sv[10], sv[11]));
    float t3 = fmaxf(fmaxf(sv[12], sv[13]), fmaxf(sv[14], sv[15]));
    float tm = fmaxf(fmaxf(t0, t1), fmaxf(t2, t3));
    tm = fmaxf(tm, __shfl_xor(tm, 16));
    tm = fmaxf(tm, __shfl_xor(tm, 32));
    const float mn = fmaxf(m, tm);
    const float sc = __expf(m - mn);
    float p[16];
    float ts = 0.f;
#pragma unroll
    for (int i = 0; i < 16; ++i) p[i] = __expf(sv[i] - mn);
    {
        float a0 = (p[0] + p[1]) + (p[2] + p[3]);
        float a1 = (p[4] + p[5]) + (p[6] + p[7]);
        float a2 = (p[8] + p[9]) + (p[10] + p[11]);
        float a3 = (p[12] + p[13]) + (p[14] + p[15]);
        ts = (a0 + a1) + (a2 + a3);
    }
    ts += __shfl_xor(ts, 16);
    ts += __shfl_xor(ts, 32);
    lsum = lsum * sc + ts;
    m = mn;
    o0 *= sc; o1 *= sc; o2 *= sc; o3 *= sc;
#pragma unroll
    for (int sub = 0; sub < 4; ++sub) {
        f16x4 pf;
        pf[0] = (f16)p[sub * 4 + 0]; pf[1] = (f16)p[sub * 4 + 1];
        pf[2] = (f16)p[sub * 4 + 2]; pf[3] = (f16)p[sub * 4 + 3];
        o0 = MFMA16(t_.v[sub * 4 + 0], pf, o0);
        o1 = MFMA16(t_.v[sub * 4 + 1], pf, o1);
        o2 = MFMA16(t_.v[sub * 4 + 2], pf, o2);
        o3 = MFMA16(t_.v[sub * 4 + 3], pf, o3);
    }
}

__global__ __launch_bounds__(256) void k_attn(const f16* __restrict__ Q,
        const f16* __restrict__ K, const f16* __restrict__ VT,
        const int* __restrict__ msk, float* __restrict__ out) {
    const int b = blockIdx.y;
    const int tq = (int)gridDim.x - 1 - (int)blockIdx.x;   // big tiles launch first
    const int w = threadIdx.x >> 6, lane = threadIdx.x & 63;
    const int col = lane & 15, g = lane >> 4;
    const int qc = tq * 64 + w * 16 + col;

    const f16* qrow = Q + ((size_t)(b * T_ + qc)) * HS_;
    f16x8 bq0 = *(const f16x8*)(qrow + g * 8);
    f16x8 bq1 = *(const f16x8*)(qrow + 32 + g * 8);

    float m = -3.0e38f, lsum = 0.f;
    f32x4 o0 = {0,0,0,0}, o1 = {0,0,0,0}, o2 = {0,0,0,0}, o3 = {0,0,0,0};
    const int* mrow = msk + b * T_;
    const f16* kb = K + (size_t)b * T_ * HS_;
    const f16* vb = VT + (size_t)b * HS_ * T_;

    Tile A, B;
    load_tile(A, 0, kb, mrow, vb, col, g);
    int it = 0;
    for (; it + 2 <= tq; it += 2) {
        load_tile(B, it + 1, kb, mrow, vb, col, g);
        compute_tile(A, it, false, bq0, bq1, qc, g, m, lsum, o0, o1, o2, o3);
        load_tile(A, it + 2, kb, mrow, vb, col, g);
        compute_tile(B, it + 1, false, bq0, bq1, qc, g, m, lsum, o0, o1, o2, o3);
    }
    if (it < tq) {
        load_tile(B, it + 1, kb, mrow, vb, col, g);
        compute_tile(A, it, false, bq0, bq1, qc, g, m, lsum, o0, o1, o2, o3);
        compute_tile(B, it + 1, true, bq0, bq1, qc, g, m, lsum, o0, o1, o2, o3);
    } else {
        compute_tile(A, it, true, bq0, bq1, qc, g, m, lsum, o0, o1, o2, o3);
    }

    const float inv = 1.0f / lsum;
    float* orow = out + ((size_t)(b * T_ + qc)) * HS_;
    float4 u;
    u.x = o0.x * inv; u.y = o0.y * inv; u.z = o0.z * inv; u.w = o0.w * inv;
    *(float4*)(orow + 0  + g * 4) = u;
    u.x = o1.x * inv; u.y = o1.y * inv; u.z = o1.z * inv; u.w = o1.w * inv;
    *(float4*)(orow + 16 + g * 4) = u;
    u.x = o2.x * inv; u.y = o2.y * inv; u.z = o2.z * inv; u.w = o2.w * inv;
    *(float4*)(orow + 32 + g * 4) = u;
    u.x = o3.x * inv; u.y = o3.y * inv; u.z = o3.z * inv; u.w = o3.w * inv;
    *(float4*)(orow + 48 + g * 4) = u;
}

// ---------------------------------------------------------------------------
extern "C" void kernel_launch(void* const* d_in, const int* in_sizes, int n_in,
                              void* d_out, int out_size, void* d_ws, size_t ws_size,
                              hipStream_t stream) {
    const float* x    = (const float*)d_in[0];
    const float* Wq   = (const float*)d_in[1];
    const float* Wk   = (const float*)d_in[2];
    const float* Wv   = (const float*)d_in[3];
    const float* fcos = (const float*)d_in[4];
    const float* fsin = (const float*)d_in[5];
    const int*   msk  = (const int*)d_in[6];

    char* ws = (char*)d_ws;
    const size_t qkv_bytes = (size_t)B_ * T_ * HS_ * sizeof(f16);   // 4 MB each
    f16* WT = (f16*)ws;                                  // 48 KB
    f16* Q  = (f16*)(ws + (1 << 16));
    f16* K  = (f16*)(ws + (1 << 16) + qkv_bytes);
    f16* VT = (f16*)(ws + (1 << 16) + 2 * qkv_bytes);

    k_wprep<<<96, 256, 0, stream>>>(Wq, Wk, Wv, WT);
    dim3 g1(T_ / 64, B_);
    k_qkv<<<g1, 256, 0, stream>>>(x, WT, fcos, fsin, Q, K, VT);
    dim3 g2(T_ / 64, B_);
    k_attn<<<g2, 256, 0, stream>>>(Q, K, VT, msk, (float*)d_out);
}

// Round 6
// 272.948 us; speedup vs baseline: 1.6253x; 1.6253x over previous
//
#include <hip/hip_runtime.h>

#define B_ 8
#define T_ 4096
#define C_ 128
#define HS_ 64

typedef _Float16 f16;
typedef _Float16 f16x8 __attribute__((ext_vector_type(8)));
typedef _Float16 f16x4 __attribute__((ext_vector_type(4)));
typedef float f32x4 __attribute__((ext_vector_type(4)));

#define MFMA32(a, b, c) __builtin_amdgcn_mfma_f32_16x16x32_f16(a, b, c, 0, 0, 0)
#define MFMA16(a, b, c) __builtin_amdgcn_mfma_f32_16x16x16f16(a, b, c, 0, 0, 0)
#define MEMBAR() asm volatile("" ::: "memory")

// ---------------------------------------------------------------------------
// Prep: WT[j][c] f16, j in [0,192): 0-63 Wq (scaled by 1/sqrt(C)), 64-127 Wk,
// 128-191 Wv.  WT row-major [192][128].
// ---------------------------------------------------------------------------
__global__ void k_wprep(const float* __restrict__ Wq, const float* __restrict__ Wk,
                        const float* __restrict__ Wv, f16* __restrict__ WT) {
    int idx = blockIdx.x * 256 + threadIdx.x;
    if (idx >= 192 * C_) return;
    int j = idx >> 7, c = idx & 127;
    const float* W = (j < 64) ? Wq : (j < 128 ? Wk : Wv);
    float v = W[c * HS_ + (j & 63)];
    if (j < 64) v *= 0.08838834764831845f;     // 1/sqrt(128), folded into q
    WT[idx] = (f16)v;
}

// ---------------------------------------------------------------------------
// QKV projection + RoPE.  OUT^T = WT · x^T via 16x16x32 MFMA.
// ---------------------------------------------------------------------------
__global__ __launch_bounds__(256) void k_qkv(const float* __restrict__ x,
        const f16* __restrict__ WT, const float* __restrict__ fcos,
        const float* __restrict__ fsin, f16* __restrict__ Q,
        f16* __restrict__ K, f16* __restrict__ VT) {
    const int b = blockIdx.y;
    const int w = threadIdx.x >> 6, lane = threadIdx.x & 63;
    const int col = lane & 15, g = lane >> 4;
    const int t = blockIdx.x * 64 + w * 16 + col;

    f16x8 bx[4];
    const float* xrow = x + ((size_t)(b * T_ + t)) * C_;
#pragma unroll
    for (int cc = 0; cc < 4; ++cc) {
        float4 x0 = *(const float4*)(xrow + cc * 32 + g * 8);
        float4 x1 = *(const float4*)(xrow + cc * 32 + g * 8 + 4);
        f16x8 v;
        v[0] = (f16)x0.x; v[1] = (f16)x0.y; v[2] = (f16)x0.z; v[3] = (f16)x0.w;
        v[4] = (f16)x1.x; v[5] = (f16)x1.y; v[6] = (f16)x1.z; v[7] = (f16)x1.w;
        bx[cc] = v;
    }

#pragma unroll
    for (int jt = 0; jt < 12; ++jt) {
        f32x4 acc = {0.f, 0.f, 0.f, 0.f};
#pragma unroll
        for (int cc = 0; cc < 4; ++cc) {
            f16x8 aw = *(const f16x8*)(WT + (size_t)(jt * 16 + col) * C_ + cc * 32 + g * 8);
            acc = MFMA32(aw, bx[cc], acc);
        }
        if (jt < 8) {
            const int hbase = (jt & 3) * 16 + g * 4;   // even head-dim base
            const int i0 = hbase >> 1;
            float c0 = fcos[t * 32 + i0],     s0 = fsin[t * 32 + i0];
            float c1 = fcos[t * 32 + i0 + 1], s1 = fsin[t * 32 + i0 + 1];
            float o0 = acc[0] * c0 - acc[1] * s0;
            float o1 = acc[0] * s0 + acc[1] * c0;
            float o2 = acc[2] * c1 - acc[3] * s1;
            float o3 = acc[2] * s1 + acc[3] * c1;
            f16x4 st; st[0] = (f16)o0; st[1] = (f16)o1; st[2] = (f16)o2; st[3] = (f16)o3;
            f16* dst = (jt < 4 ? Q : K);
            *(f16x4*)(dst + ((size_t)(b * T_ + t)) * HS_ + hbase) = st;
        } else {
            const int dbase = (jt - 8) * 16 + g * 4;
#pragma unroll
            for (int r = 0; r < 4; ++r)
                VT[((size_t)(b * HS_ + dbase + r)) * T_ + t] = (f16)acc[r];
        }
    }
}

// ---------------------------------------------------------------------------
// Flash attention, KVBLK=32, register double-buffer protected by asm memory
// barriers (loads cannot cross a "memory" clobber, so the compiler cannot
// sink the prefetch into the compute phase).
// 512-thread blocks, grid (32, B): waves 0-3 -> q-tile x, waves 4-7 ->
// q-tile 63-x  => per-SIMD work is (a+1)+(64-a) tiles everywhere (balanced),
// exactly 1 block per CU.
// ---------------------------------------------------------------------------
struct Tile32 {
    f16x8 k[4];     // 2 subtiles x 2
    int4  mk[2];
    f16x4 v[8];     // [sub][mt]
};

__device__ __forceinline__ void load_tile32(Tile32& t_, int it, const f16* __restrict__ kb,
        const int* __restrict__ mrow, const f16* __restrict__ vb, int col, int g) {
    const int kv0 = it * 32;
#pragma unroll
    for (int sub = 0; sub < 2; ++sub) {
        const f16* krow = kb + (size_t)(kv0 + sub * 16 + col) * HS_;
        t_.k[sub * 2]     = *(const f16x8*)(krow + g * 8);
        t_.k[sub * 2 + 1] = *(const f16x8*)(krow + 32 + g * 8);
        t_.mk[sub] = *(const int4*)(mrow + kv0 + sub * 16 + g * 4);
#pragma unroll
        for (int mt = 0; mt < 4; ++mt)
            t_.v[sub * 4 + mt] = *(const f16x4*)(vb + (size_t)(col + 16 * mt) * T_ + kv0 + sub * 16 + g * 4);
    }
}

__device__ __forceinline__ void compute_tile32(const Tile32& t_, int it, bool last,
        f16x8 bq0, f16x8 bq1, int qc, int g,
        float& m, float& lsum, f32x4& o0, f32x4& o1, f32x4& o2, f32x4& o3) {
    float sv[8];
#pragma unroll
    for (int sub = 0; sub < 2; ++sub) {
        f32x4 s = {0.f, 0.f, 0.f, 0.f};
        s = MFMA32(t_.k[sub * 2], bq0, s);
        s = MFMA32(t_.k[sub * 2 + 1], bq1, s);
        const int4 mk = t_.mk[sub];
        const int kbase = it * 32 + sub * 16 + g * 4;
        bool c0 = mk.x != 0, c1 = mk.y != 0, c2 = mk.z != 0, c3 = mk.w != 0;
        if (last) {
            c0 = c0 && (kbase + 0 <= qc); c1 = c1 && (kbase + 1 <= qc);
            c2 = c2 && (kbase + 2 <= qc); c3 = c3 && (kbase + 3 <= qc);
        }
        sv[sub * 4 + 0] = c0 ? s.x : -1e30f;
        sv[sub * 4 + 1] = c1 ? s.y : -1e30f;
        sv[sub * 4 + 2] = c2 ? s.z : -1e30f;
        sv[sub * 4 + 3] = c3 ? s.w : -1e30f;
    }
    float t0 = fmaxf(fmaxf(sv[0], sv[1]), fmaxf(sv[2], sv[3]));
    float t1 = fmaxf(fmaxf(sv[4], sv[5]), fmaxf(sv[6], sv[7]));
    float tm = fmaxf(t0, t1);
    tm = fmaxf(tm, __shfl_xor(tm, 16));
    tm = fmaxf(tm, __shfl_xor(tm, 32));
    const float mn = fmaxf(m, tm);
    const float sc = __expf(m - mn);
    float p[8];
#pragma unroll
    for (int i = 0; i < 8; ++i) p[i] = __expf(sv[i] - mn);
    float ts = ((p[0] + p[1]) + (p[2] + p[3])) + ((p[4] + p[5]) + (p[6] + p[7]));
    ts += __shfl_xor(ts, 16);
    ts += __shfl_xor(ts, 32);
    lsum = lsum * sc + ts;
    m = mn;
    o0 *= sc; o1 *= sc; o2 *= sc; o3 *= sc;
#pragma unroll
    for (int sub = 0; sub < 2; ++sub) {
        f16x4 pf;
        pf[0] = (f16)p[sub * 4 + 0]; pf[1] = (f16)p[sub * 4 + 1];
        pf[2] = (f16)p[sub * 4 + 2]; pf[3] = (f16)p[sub * 4 + 3];
        o0 = MFMA16(t_.v[sub * 4 + 0], pf, o0);
        o1 = MFMA16(t_.v[sub * 4 + 1], pf, o1);
        o2 = MFMA16(t_.v[sub * 4 + 2], pf, o2);
        o3 = MFMA16(t_.v[sub * 4 + 3], pf, o3);
    }
}

__global__ __launch_bounds__(512) void k_attn(const f16* __restrict__ Q,
        const f16* __restrict__ K, const f16* __restrict__ VT,
        const int* __restrict__ msk, float* __restrict__ out) {
    const int b = blockIdx.y;
    const int w = threadIdx.x >> 6, lane = threadIdx.x & 63;
    const int col = lane & 15, g = lane >> 4;
    const int w4 = w & 3;
    const int tq = (w < 4) ? (int)blockIdx.x : (63 - (int)blockIdx.x);
    const int qc = tq * 64 + w4 * 16 + col;
    const int itLast = (tq * 64 + w4 * 16 + 15) >> 5;   // wave-uniform

    const f16* qrow = Q + ((size_t)(b * T_ + qc)) * HS_;
    f16x8 bq0 = *(const f16x8*)(qrow + g * 8);
    f16x8 bq1 = *(const f16x8*)(qrow + 32 + g * 8);

    float m = -3.0e38f, lsum = 0.f;
    f32x4 o0 = {0,0,0,0}, o1 = {0,0,0,0}, o2 = {0,0,0,0}, o3 = {0,0,0,0};
    const int* mrow = msk + b * T_;
    const f16* kb = K + (size_t)b * T_ * HS_;
    const f16* vb = VT + (size_t)b * HS_ * T_;

    Tile32 A, Bt;
    load_tile32(A, 0, kb, mrow, vb, col, g);
    int it = 0;
    for (; it + 2 <= itLast; it += 2) {
        load_tile32(Bt, it + 1, kb, mrow, vb, col, g);
        MEMBAR();
        compute_tile32(A, it, false, bq0, bq1, qc, g, m, lsum, o0, o1, o2, o3);
        load_tile32(A, it + 2, kb, mrow, vb, col, g);
        MEMBAR();
        compute_tile32(Bt, it + 1, false, bq0, bq1, qc, g, m, lsum, o0, o1, o2, o3);
    }
    if (it < itLast) {
        load_tile32(Bt, it + 1, kb, mrow, vb, col, g);
        MEMBAR();
        compute_tile32(A, it, false, bq0, bq1, qc, g, m, lsum, o0, o1, o2, o3);
        compute_tile32(Bt, it + 1, true, bq0, bq1, qc, g, m, lsum, o0, o1, o2, o3);
    } else {
        compute_tile32(A, it, true, bq0, bq1, qc, g, m, lsum, o0, o1, o2, o3);
    }

    const float inv = 1.0f / lsum;
    float* orow = out + ((size_t)(b * T_ + qc)) * HS_;
    float4 u;
    u.x = o0.x * inv; u.y = o0.y * inv; u.z = o0.z * inv; u.w = o0.w * inv;
    *(float4*)(orow + 0  + g * 4) = u;
    u.x = o1.x * inv; u.y = o1.y * inv; u.z = o1.z * inv; u.w = o1.w * inv;
    *(float4*)(orow + 16 + g * 4) = u;
    u.x = o2.x * inv; u.y = o2.y * inv; u.z = o2.z * inv; u.w = o2.w * inv;
    *(float4*)(orow + 32 + g * 4) = u;
    u.x = o3.x * inv; u.y = o3.y * inv; u.z = o3.z * inv; u.w = o3.w * inv;
    *(float4*)(orow + 48 + g * 4) = u;
}

// ---------------------------------------------------------------------------
extern "C" void kernel_launch(void* const* d_in, const int* in_sizes, int n_in,
                              void* d_out, int out_size, void* d_ws, size_t ws_size,
                              hipStream_t stream) {
    const float* x    = (const float*)d_in[0];
    const float* Wq   = (const float*)d_in[1];
    const float* Wk   = (const float*)d_in[2];
    const float* Wv   = (const float*)d_in[3];
    const float* fcos = (const float*)d_in[4];
    const float* fsin = (const float*)d_in[5];
    const int*   msk  = (const int*)d_in[6];

    char* ws = (char*)d_ws;
    const size_t qkv_bytes = (size_t)B_ * T_ * HS_ * sizeof(f16);   // 4 MB each
    f16* WT = (f16*)ws;                                  // 48 KB
    f16* Q  = (f16*)(ws + (1 << 16));
    f16* K  = (f16*)(ws + (1 << 16) + qkv_bytes);
    f16* VT = (f16*)(ws + (1 << 16) + 2 * qkv_bytes);

    k_wprep<<<96, 256, 0, stream>>>(Wq, Wk, Wv, WT);
    dim3 g1(T_ / 64, B_);
    k_qkv<<<g1, 256, 0, stream>>>(x, WT, fcos, fsin, Q, K, VT);
    dim3 g2(32, B_);
    k_attn<<<g2, 512, 0, stream>>>(Q, K, VT, msk, (float*)d_out);
}